// Round 13
// baseline (228.789 us; speedup 1.0000x reference)
//
#include <hip/hip_runtime.h>
#include <hip/hip_bf16.h>
#include <cstdint>
#include <cstddef>

#define BB 2
#define NN 2048
#define CC 768
#define HH 12
#define DD 64
#define HID 3072
#define TT (BB*NN)   // 4096 tokens

typedef __attribute__((ext_vector_type(8))) short bf16x8;
typedef __attribute__((ext_vector_type(4))) short bf16x4;
typedef __attribute__((ext_vector_type(4))) float f32x4;

__device__ __forceinline__ unsigned short f2bf(float f) {
    unsigned int u = __float_as_uint(f);
    u += 0x7fffu + ((u >> 16) & 1u);
    return (unsigned short)(u >> 16);
}
__device__ __forceinline__ float bf2f(unsigned short u) {
    return __uint_as_float(((unsigned int)u) << 16);
}
#if __has_builtin(__builtin_amdgcn_exp2f)
#define EXP2F(x) __builtin_amdgcn_exp2f(x)
#else
#define EXP2F(x) exp2f(x)
#endif

// async global -> LDS, 16 bytes per lane (dest must be base + lane*16)
__device__ __forceinline__ void gload16(const void* g, void* l) {
    __builtin_amdgcn_global_load_lds((__attribute__((address_space(1))) unsigned int*)g,
                                     (__attribute__((address_space(3))) unsigned int*)l,
                                     16, 0, 0);
}

#define WAITV(N) asm volatile("s_waitcnt vmcnt(" #N ")" ::: "memory")
#define WAITLGKM asm volatile("s_waitcnt lgkmcnt(0)" ::: "memory")

typedef __attribute__((ext_vector_type(4))) float float4v;
typedef __attribute__((ext_vector_type(4))) unsigned short ushort4v;

// ---------------- fused prep: LN1 (blocks 0..4095) + cvt (4096..5119) + maskbits (5120..6143) ----
struct PrepArgs {
    const float* x; const float* g1; const float* b1; unsigned short* xn;
    const float* cin[5]; unsigned short* cout[5]; int n4[5];
    const float* mask; unsigned short* mb;
};
__global__ __launch_bounds__(256) void prep_kernel(PrepArgs a) {
    int id = blockIdx.x;
    int tid = threadIdx.x;
    if (id < TT) {
        const float* xr = a.x + (size_t)id * CC;
        float v0 = xr[tid], v1 = xr[tid + 256], v2 = xr[tid + 512];
        float s = v0 + v1 + v2;
        float s2 = v0 * v0 + v1 * v1 + v2 * v2;
#pragma unroll
        for (int off = 1; off < 64; off <<= 1) {
            s  += __shfl_xor(s, off);
            s2 += __shfl_xor(s2, off);
        }
        __shared__ float red[8];
        int wv = tid >> 6, lane = tid & 63;
        if (lane == 0) { red[wv] = s; red[wv + 4] = s2; }
        __syncthreads();
        s  = red[0] + red[1] + red[2] + red[3];
        s2 = red[4] + red[5] + red[6] + red[7];
        float mu   = s * (1.0f / CC);
        float var  = s2 * (1.0f / CC) - mu * mu;
        float rstd = rsqrtf(var + 1e-5f);
        unsigned short* orow = a.xn + (size_t)id * CC;
        orow[tid]       = f2bf((v0 - mu) * rstd * a.g1[tid]       + a.b1[tid]);
        orow[tid + 256] = f2bf((v1 - mu) * rstd * a.g1[tid + 256] + a.b1[tid + 256]);
        orow[tid + 512] = f2bf((v2 - mu) * rstd * a.g1[tid + 512] + a.b1[tid + 512]);
    } else if (id < TT + 1024) {
        int base = (id - TT) * 256 + tid;
        int stride = 1024 * 256;
#pragma unroll
        for (int sseg = 0; sseg < 5; ++sseg) {
            const float4v* ip = (const float4v*)a.cin[sseg];
            ushort4v* op = (ushort4v*)a.cout[sseg];
            for (int i = base; i < a.n4[sseg]; i += stride) {
                float4v v = ip[i];
                ushort4v o;
                o[0] = f2bf(v[0]); o[1] = f2bf(v[1]); o[2] = f2bf(v[2]); o[3] = f2bf(v[3]);
                op[i] = o;
            }
        }
    } else {
        int base = (id - TT - 1024) * 256 + tid;
        int stride = 1024 * 256;
        int n = BB * NN * (NN / 16);
        for (int i = base; i < n; i += stride) {
            const float4v* mp = (const float4v*)(a.mask + (size_t)i * 16);
            unsigned int bits = 0;
#pragma unroll
            for (int q = 0; q < 4; ++q) {
                float4v v = mp[q];
#pragma unroll
                for (int j = 0; j < 4; ++j) bits |= (v[j] > 0.5f) ? (1u << (q * 4 + j)) : 0u;
            }
            a.mb[i] = (unsigned short)bits;
        }
    }
}

// ---------------- LayerNorm (standalone, for LN2) ----------------
__global__ __launch_bounds__(256) void ln_kernel(const float* __restrict__ x,
                                                 const float* __restrict__ g,
                                                 const float* __restrict__ b,
                                                 unsigned short* __restrict__ out) {
    int t = blockIdx.x;
    int tid = threadIdx.x;
    const float* xr = x + (size_t)t * CC;
    float v0 = xr[tid], v1 = xr[tid + 256], v2 = xr[tid + 512];
    float s = v0 + v1 + v2;
    float s2 = v0 * v0 + v1 * v1 + v2 * v2;
#pragma unroll
    for (int off = 1; off < 64; off <<= 1) {
        s  += __shfl_xor(s, off);
        s2 += __shfl_xor(s2, off);
    }
    __shared__ float red[8];
    int wv = tid >> 6, lane = tid & 63;
    if (lane == 0) { red[wv] = s; red[wv + 4] = s2; }
    __syncthreads();
    s  = red[0] + red[1] + red[2] + red[3];
    s2 = red[4] + red[5] + red[6] + red[7];
    float mu   = s * (1.0f / CC);
    float var  = s2 * (1.0f / CC) - mu * mu;
    float rstd = rsqrtf(var + 1e-5f);
    unsigned short* orow = out + (size_t)t * CC;
    orow[tid]       = f2bf((v0 - mu) * rstd * g[tid]       + b[tid]);
    orow[tid + 256] = f2bf((v1 - mu) * rstd * g[tid + 256] + b[tid + 256]);
    orow[tid + 512] = f2bf((v2 - mu) * rstd * g[tid + 512] + b[tid + 512]);
}

// ---------------- GEMM (R9 template, BM=64 everywhere): dbuf + counted vmcnt ----
// C[M,N] = A[M,K] @ Bw[N,K]^T (+epilogue). BK=32, BN=128. BM=64: 24KB LDS ->
// 6 blocks/CU; grids 384-1536 blocks. Healthy compile point: 76 VGPR (R9/R10).
// EPI 0: bf16; 1: +bias+res->f32; 2: +bias+GELU->bf16; 3: +bias+res->f32
template <int EPI, int BM>
__global__ __launch_bounds__(256) void gemm_bt(const unsigned short* __restrict__ A,
                                               const unsigned short* __restrict__ Bw,
                                               const float* __restrict__ bias,
                                               const float* __restrict__ res,
                                               void* __restrict__ out,
                                               int M, int N, int K) {
    constexpr int MI = BM / 32;           // 2 (BM=64)
    constexpr int NCA = (BM * 4) / 256;   // A chunks per thread: 1
    __shared__ alignas(16) unsigned short As[2][BM * 32];
    __shared__ alignas(16) unsigned short Bs[2][128 * 32];
    int tid = threadIdx.x;
    int lane = tid & 63, wv = tid >> 6;
    int l16 = lane & 15, lg = lane >> 4;
    int bm = blockIdx.x, bn = blockIdx.y;
    int wm = (wv & 1) * (BM / 2), wn = (wv >> 1) * 64;

    const unsigned short* Ab = A + (size_t)bm * BM * K;
    const unsigned short* Bb = Bw + (size_t)bn * 128 * K;

    const unsigned short* aSrc[NCA]; int aDst[NCA];
#pragma unroll
    for (int i = 0; i < NCA; ++i) {
        int c = tid + i * 256;
        int row = c >> 2, p = c & 3;
        int lc = p ^ ((row >> 1) & 3);
        aSrc[i] = Ab + (size_t)row * K + lc * 8;
        aDst[i] = c * 8;
    }
    const unsigned short* bSrc[2]; int bDst[2];
#pragma unroll
    for (int i = 0; i < 2; ++i) {
        int c = tid + i * 256;
        int row = c >> 2, p = c & 3;
        int lc = p ^ ((row >> 1) & 3);
        bSrc[i] = Bb + (size_t)row * K + lc * 8;
        bDst[i] = c * 8;
    }
    int aoff = (wm + l16) * 32 + ((lg ^ (((wm + l16) >> 1) & 3)) * 8);
    int boff = (wn + l16) * 32 + ((lg ^ (((wn + l16) >> 1) & 3)) * 8);

    f32x4 acc[MI][4];
#pragma unroll
    for (int i = 0; i < MI; ++i)
#pragma unroll
        for (int j = 0; j < 4; ++j) acc[i][j] = f32x4{0.f, 0.f, 0.f, 0.f};

    auto STAGE = [&](int s, int k0) {
#pragma unroll
        for (int i = 0; i < NCA; ++i) gload16(aSrc[i] + k0, &As[s][aDst[i]]);
#pragma unroll
        for (int i = 0; i < 2; ++i)   gload16(bSrc[i] + k0, &Bs[s][bDst[i]]);
    };

    STAGE(0, 0);
    int nt = K / 32;
    for (int t = 0; t < nt; ++t) {
        int cur = t & 1;
        if (t + 1 < nt) {
            STAGE(cur ^ 1, (t + 1) * 32);
            if constexpr (NCA + 2 == 4) { WAITV(4); } else { WAITV(3); }
        } else {
            WAITV(0);
        }
        __builtin_amdgcn_s_barrier();
        bf16x8 af[MI], bfr[4];
#pragma unroll
        for (int mi = 0; mi < MI; ++mi) af[mi]  = *(const bf16x8*)&As[cur][aoff + mi * 512];
#pragma unroll
        for (int ni = 0; ni < 4; ++ni)  bfr[ni] = *(const bf16x8*)&Bs[cur][boff + ni * 512];
#pragma unroll
        for (int mi = 0; mi < MI; ++mi)
#pragma unroll
            for (int ni = 0; ni < 4; ++ni)
                acc[mi][ni] = __builtin_amdgcn_mfma_f32_16x16x32_bf16(bfr[ni], af[mi], acc[mi][ni], 0, 0, 0);
        WAITLGKM;
        __builtin_amdgcn_s_barrier();
    }

    // vector epilogue: row = ...+l16, cols = base+lg*4+(0..3)
#pragma unroll
    for (int mi = 0; mi < MI; ++mi) {
        int row = bm * BM + wm + mi * 16 + l16;
#pragma unroll
        for (int ni = 0; ni < 4; ++ni) {
            int col = bn * 128 + wn + ni * 16 + lg * 4;
            size_t idx = (size_t)row * N + col;
            f32x4 v = acc[mi][ni];
            if (EPI == 0) {
                bf16x4 ov;
#pragma unroll
                for (int r2 = 0; r2 < 4; ++r2) ov[r2] = (short)f2bf(v[r2]);
                *(bf16x4*)((unsigned short*)out + idx) = ov;
            } else if (EPI == 1 || EPI == 3) {
                f32x4 bv = *(const f32x4*)&bias[col];
                f32x4 rv = *(const f32x4*)&res[idx];
                f32x4 ov;
#pragma unroll
                for (int r2 = 0; r2 < 4; ++r2) ov[r2] = v[r2] + bv[r2] + rv[r2];
                *(f32x4*)((float*)out + idx) = ov;
            } else {
                f32x4 bv = *(const f32x4*)&bias[col];
                bf16x4 ov;
#pragma unroll
                for (int r2 = 0; r2 < 4; ++r2) {
                    float t2 = v[r2] + bv[r2];
                    t2 = 0.5f * t2 * (1.0f + erff(t2 * 0.70710678118f));
                    ov[r2] = (short)f2bf(t2);
                }
                *(bf16x4*)((unsigned short*)out + idx) = ov;
            }
        }
    }
}

// ---------------- Flash attention v8: SINGLE raw barrier, counted vmcnt ----------------
// The R12 (and earlier) version used __syncthreads per tile, whose implicit
// vmcnt(0) drained the K-dma issued THE SAME ITERATION for tile kt+1 ->
// prefetch structurally defeated. New schedule per iter:
//   WAITV(0)   : only prev iter's 2 K-dma outstanding (had a full iter to fly)
//   lgkmcnt(0) : my Vt writes + K ds_reads drained
//   s_barrier  : all waves' Ks[cur]/Vt[cur] visible; safe to overwrite [cur^1]
//   LOAD(kt+1) : issued AFTER barrier (no writer-vs-lagging-reader race)
//   compute    : QK^T + exp2 softmax (no max; shift-free, overflow-safe) + PV
//   WAITV(2)   : V/mask landed (sched_barrier pins them before the K-dma);
//                K-dma for kt+1 stays in flight across the next barrier
//   WRITEV     : pack V^T into Vt[cur^1]
#define KVB 64
#define ANT (NN/KVB)   // 32 tiles
#define VP 68          // Vt pitch (ushorts)
__global__ __launch_bounds__(256) void attn_kernel(const unsigned short* __restrict__ qkv,
                                                   const unsigned short* __restrict__ maskb,
                                                   unsigned short* __restrict__ o) {
    __shared__ alignas(16) unsigned short Ks[2][64 * 64];
    __shared__ alignas(16) unsigned short Vt[2][64 * VP];
    int tid = threadIdx.x;
    int lane = tid & 63, wv = tid >> 6;
    int l16 = lane & 15, lg = lane >> 4;
    int id = blockIdx.x;                 // 0..767
    int xcd = id & 7, r = id >> 3;       // r 0..95
    int bh = xcd * 3 + (r % 3);          // 0..23
    int qb = r / 3;                      // 0..31
    int b = bh / HH, h = bh % HH;
    int qrow = qb * 64 + wv * 16 + l16;

    const unsigned short* qp = qkv + ((size_t)(b * NN + qrow)) * 2304 + h * DD;
    bf16x8 q0r = *(const bf16x8*)(qp + 8 * lg);
    bf16x8 q1r = *(const bf16x8*)(qp + 32 + 8 * lg);
    const float QSC = 0.125f * 1.4426950408889634f;
    bf16x8 q0, q1;
#pragma unroll
    for (int j = 0; j < 8; ++j) {
        q0[j] = (short)f2bf(bf2f((unsigned short)q0r[j]) * QSC);
        q1[j] = (short)f2bf(bf2f((unsigned short)q1r[j]) * QSC);
    }

    const unsigned short* mrow  = maskb + ((size_t)(b * NN + qrow)) * 128;
    const unsigned short* kbase = qkv + (size_t)b * NN * 2304 + 768 + h * DD;
    const unsigned short* vbase = qkv + (size_t)b * NN * 2304 + 1536 + h * DD;

    const unsigned short* kSrc[2]; int kDst[2];
#pragma unroll
    for (int i = 0; i < 2; ++i) {
        int c = tid + i * 256;
        int row = c >> 3, p = c & 7;
        int lc = p ^ (row & 7);
        kSrc[i] = kbase + (size_t)row * 2304 + lc * 8;
        kDst[i] = c * 8;
    }
    int kp = tid & 31, dg = tid >> 5;
    const unsigned short* vSrc = vbase + (size_t)(2 * kp) * 2304 + dg * 8;

    int sw = l16 & 7;
    int kb0 = l16 * 64 + ((lg ^ sw) * 8);
    int kb1 = l16 * 64 + (((lg + 4) ^ sw) * 8);
    int vbo = l16 * VP + lg * 4;

    bf16x8 va, vb;
    unsigned long long mb_cur, mb_nxt;

    f32x4 oa[4];
#pragma unroll
    for (int i = 0; i < 4; ++i) oa[i] = f32x4{0.f, 0.f, 0.f, 0.f};
    float lrun = 0.f;

    // V + mask FIRST, then K-dma: counted WAITV(2) leaves only K-dma in flight.
    auto LOAD = [&](int t, int s) {
        const unsigned short* vp = vSrc + (size_t)t * KVB * 2304;
        va = *(const bf16x8*)(vp);
        vb = *(const bf16x8*)(vp + 2304);
        mb_nxt = *(const unsigned long long*)(mrow + t * 4);
        __builtin_amdgcn_sched_barrier(0);   // pin V/mask issue before K-dma
#pragma unroll
        for (int i = 0; i < 2; ++i) gload16(kSrc[i] + (size_t)t * KVB * 2304, &Ks[s][kDst[i]]);
    };
    auto WRITEV = [&](int s) {
        unsigned int* VtU = (unsigned int*)Vt[s];
#pragma unroll
        for (int j = 0; j < 8; ++j)
            VtU[(dg * 8 + j) * (VP / 2) + kp] =
                (unsigned int)(unsigned short)va[j] | ((unsigned int)(unsigned short)vb[j] << 16);
    };

    LOAD(0, 0);
    WAITV(2);          // va/vb/mask landed; K-dma(2) in flight
    WRITEV(0);
    mb_cur = mb_nxt;
    int cur = 0;

    for (int kt = 0; kt < ANT; ++kt) {
        bool pre = (kt + 1 < ANT);
        WAITV(0);                          // my Ks[cur] dma chunks complete
        WAITLGKM;                          // my Vt[cur] writes / K reads drained
        __builtin_amdgcn_s_barrier();      // everyone's [cur] visible
        if (pre) LOAD(kt + 1, cur ^ 1);    // after barrier: no lagging readers

        const unsigned short* Ksc = Ks[cur];
        const unsigned short* Vtc = Vt[cur];

        // ---- QK^T + direct exp2 (no max subtraction) ----
        float ps = 0.f;
        bf16x4 pf[4];
#pragma unroll
        for (int ks = 0; ks < 4; ++ks) {
            bf16x8 k0 = *(const bf16x8*)&Ksc[kb0 + ks * 1024];
            bf16x8 k1 = *(const bf16x8*)&Ksc[kb1 + ks * 1024];
            f32x4 sa = f32x4{0.f, 0.f, 0.f, 0.f};
            sa = __builtin_amdgcn_mfma_f32_16x16x32_bf16(k0, q0, sa, 0, 0, 0);
            sa = __builtin_amdgcn_mfma_f32_16x16x32_bf16(k1, q1, sa, 0, 0, 0);
            unsigned int m16 = (unsigned int)(mb_cur >> (ks * 16 + lg * 4));
#pragma unroll
            for (int r2 = 0; r2 < 4; ++r2) {
                float mbit = (float)((m16 >> r2) & 1u);
                float p = EXP2F(fmaf(mbit, -144269.5f, sa[r2]));
                ps += p;
                pf[ks][r2] = (short)(__float_as_uint(p) >> 16);   // truncating bf16 (p>=0)
            }
        }
        lrun += ps;

        // ---- PV: O^T[d][qrow] += V^T[d][key] * P^T[key][qrow] ----
#pragma unroll
        for (int ks = 0; ks < 4; ++ks)
#pragma unroll
            for (int db = 0; db < 4; ++db) {
                bf16x4 vf = *(const bf16x4*)&Vtc[vbo + db * 16 * VP + ks * 16];
                oa[db] = __builtin_amdgcn_mfma_f32_16x16x16bf16_1k(vf, pf[ks], oa[db], 0, 0, 0);
            }

        if (pre) {
            WAITV(2);                      // va/vb/mask for kt+1 landed
            WRITEV(cur ^ 1);
            cur ^= 1;
            mb_cur = mb_nxt;
        }
    }

    float lt = lrun;
    lt += __shfl_xor(lt, 16);
    lt += __shfl_xor(lt, 32);
    float inv = 1.0f / lt;
    unsigned short* op = o + ((size_t)(b * NN + qrow)) * CC + h * DD;
#pragma unroll
    for (int db = 0; db < 4; ++db) {
        bf16x4 ov;
#pragma unroll
        for (int r2 = 0; r2 < 4; ++r2) ov[r2] = (short)f2bf(oa[db][r2] * inv);
        *(bf16x4*)&op[db * 16 + lg * 4] = ov;
    }
}

// ---------------- host launch ----------------
extern "C" void kernel_launch(void* const* d_in, const int* in_sizes, int n_in,
                              void* d_out, int out_size, void* d_ws, size_t ws_size,
                              hipStream_t stream) {
    const float* x    = (const float*)d_in[0];
    const float* mask = (const float*)d_in[1];
    const float* g1   = (const float*)d_in[2];
    const float* b1   = (const float*)d_in[3];
    const float* Wq   = (const float*)d_in[4];
    const float* Wkv  = (const float*)d_in[5];
    const float* Wp   = (const float*)d_in[6];
    const float* bp   = (const float*)d_in[7];
    const float* g2   = (const float*)d_in[8];
    const float* b2   = (const float*)d_in[9];
    const float* W1   = (const float*)d_in[10];
    const float* bf1  = (const float*)d_in[11];
    const float* W2   = (const float*)d_in[12];
    const float* bf2  = (const float*)d_in[13];
    float* out = (float*)d_out;

    char* w = (char*)d_ws;
    unsigned short* wqkv = (unsigned short*)w;      w += (size_t)2304 * 768 * 2;
    unsigned short* wp   = (unsigned short*)w;      w += (size_t)768 * 768 * 2;
    unsigned short* w1   = (unsigned short*)w;      w += (size_t)3072 * 768 * 2;
    unsigned short* w2   = (unsigned short*)w;      w += (size_t)768 * 3072 * 2;
    unsigned short* xn   = (unsigned short*)w;      w += (size_t)TT * CC * 2;
    unsigned short* qkv  = (unsigned short*)w;      w += (size_t)TT * 2304 * 2;
    unsigned short* mb   = (unsigned short*)w;      w += (size_t)BB * NN * 128 * 2;
    unsigned short* obuf = (unsigned short*)w;      w += (size_t)TT * CC * 2;
    float*          x1   = (float*)w;               w += (size_t)TT * CC * 4;
    unsigned short* xn2  = (unsigned short*)w;      w += (size_t)TT * CC * 2;
    unsigned short* hbuf = (unsigned short*)w;      w += (size_t)TT * HID * 2;

    PrepArgs pa;
    pa.x = x; pa.g1 = g1; pa.b1 = b1; pa.xn = xn;
    pa.cin[0] = Wq;  pa.cout[0] = wqkv;             pa.n4[0] = 768 * 768 / 4;
    pa.cin[1] = Wkv; pa.cout[1] = wqkv + 768 * 768; pa.n4[1] = 1536 * 768 / 4;
    pa.cin[2] = Wp;  pa.cout[2] = wp;               pa.n4[2] = 768 * 768 / 4;
    pa.cin[3] = W1;  pa.cout[3] = w1;               pa.n4[3] = 3072 * 768 / 4;
    pa.cin[4] = W2;  pa.cout[4] = w2;               pa.n4[4] = 768 * 3072 / 4;
    pa.mask = mask; pa.mb = mb;
    prep_kernel<<<TT + 2048, 256, 0, stream>>>(pa);

    // qkv: M=4096 N=2304 K=768 -> grid 64 x 18 = 1152
    gemm_bt<0, 64><<<dim3(TT / 64, 2304 / 128), 256, 0, stream>>>(xn, wqkv, nullptr, nullptr, qkv, TT, 2304, 768);

    attn_kernel<<<32 * 24, 256, 0, stream>>>(qkv, mb, obuf);

    // proj: M=4096 N=768 K=768 -> grid 64 x 6 = 384
    gemm_bt<1, 64><<<dim3(TT / 64, 768 / 128), 256, 0, stream>>>(obuf, wp, bp, x, x1, TT, 768, 768);

    ln_kernel<<<TT, 256, 0, stream>>>(x1, g2, b2, xn2);

    // fc1: M=4096 N=3072 K=768 -> grid 64 x 24 = 1536 (6 blocks/CU, 24 waves/CU)
    gemm_bt<2, 64><<<dim3(TT / 64, HID / 128), 256, 0, stream>>>(xn2, w1, bf1, nullptr, hbuf, TT, HID, 768);

    // fc2: M=4096 N=768 K=3072 -> grid 64 x 6 = 384
    gemm_bt<3, 64><<<dim3(TT / 64, 768 / 128), 256, 0, stream>>>(hbuf, w2, bf2, x1, out, TT, 768, HID);
}

// Round 14
// 218.740 us; speedup vs baseline: 1.0459x; 1.0459x over previous
//
#include <hip/hip_runtime.h>
#include <hip/hip_bf16.h>
#include <cstdint>
#include <cstddef>

#define BB 2
#define NN 2048
#define CC 768
#define HH 12
#define DD 64
#define HID 3072
#define TT (BB*NN)   // 4096 tokens

typedef __attribute__((ext_vector_type(8))) short bf16x8;
typedef __attribute__((ext_vector_type(4))) short bf16x4;
typedef __attribute__((ext_vector_type(4))) float f32x4;
typedef __attribute__((ext_vector_type(4))) float float4v;
typedef __attribute__((ext_vector_type(4))) unsigned short ushort4v;
typedef __attribute__((ext_vector_type(8))) unsigned short ushort8v;

__device__ __forceinline__ unsigned short f2bf(float f) {
    unsigned int u = __float_as_uint(f);
    u += 0x7fffu + ((u >> 16) & 1u);
    return (unsigned short)(u >> 16);
}
__device__ __forceinline__ float bf2f(unsigned short u) {
    return __uint_as_float(((unsigned int)u) << 16);
}
#if __has_builtin(__builtin_amdgcn_exp2f)
#define EXP2F(x) __builtin_amdgcn_exp2f(x)
#else
#define EXP2F(x) exp2f(x)
#endif

// async global -> LDS, 16 bytes per lane (dest must be base + lane*16)
__device__ __forceinline__ void gload16(const void* g, void* l) {
    __builtin_amdgcn_global_load_lds((__attribute__((address_space(1))) unsigned int*)g,
                                     (__attribute__((address_space(3))) unsigned int*)l,
                                     16, 0, 0);
}

#define WAITV(N) asm volatile("s_waitcnt vmcnt(" #N ")" ::: "memory")
#define WAITLGKM asm volatile("s_waitcnt lgkmcnt(0)" ::: "memory")

// ---------------- fused prep: LN1 (blocks 0..4095) + cvt (4096..5119) + maskbits (5120..6143) ----
struct PrepArgs {
    const float* x; const float* g1; const float* b1; unsigned short* xn;
    const float* cin[5]; unsigned short* cout[5]; int n4[5];
    const float* mask; unsigned short* mb;
};
__global__ __launch_bounds__(256) void prep_kernel(PrepArgs a) {
    int id = blockIdx.x;
    int tid = threadIdx.x;
    if (id < TT) {
        const float* xr = a.x + (size_t)id * CC;
        float v0 = xr[tid], v1 = xr[tid + 256], v2 = xr[tid + 512];
        float s = v0 + v1 + v2;
        float s2 = v0 * v0 + v1 * v1 + v2 * v2;
#pragma unroll
        for (int off = 1; off < 64; off <<= 1) {
            s  += __shfl_xor(s, off);
            s2 += __shfl_xor(s2, off);
        }
        __shared__ float red[8];
        int wv = tid >> 6, lane = tid & 63;
        if (lane == 0) { red[wv] = s; red[wv + 4] = s2; }
        __syncthreads();
        s  = red[0] + red[1] + red[2] + red[3];
        s2 = red[4] + red[5] + red[6] + red[7];
        float mu   = s * (1.0f / CC);
        float var  = s2 * (1.0f / CC) - mu * mu;
        float rstd = rsqrtf(var + 1e-5f);
        unsigned short* orow = a.xn + (size_t)id * CC;
        orow[tid]       = f2bf((v0 - mu) * rstd * a.g1[tid]       + a.b1[tid]);
        orow[tid + 256] = f2bf((v1 - mu) * rstd * a.g1[tid + 256] + a.b1[tid + 256]);
        orow[tid + 512] = f2bf((v2 - mu) * rstd * a.g1[tid + 512] + a.b1[tid + 512]);
    } else if (id < TT + 1024) {
        int base = (id - TT) * 256 + tid;
        int stride = 1024 * 256;
#pragma unroll
        for (int sseg = 0; sseg < 5; ++sseg) {
            const float4v* ip = (const float4v*)a.cin[sseg];
            ushort4v* op = (ushort4v*)a.cout[sseg];
            for (int i = base; i < a.n4[sseg]; i += stride) {
                float4v v = ip[i];
                ushort4v o;
                o[0] = f2bf(v[0]); o[1] = f2bf(v[1]); o[2] = f2bf(v[2]); o[3] = f2bf(v[3]);
                op[i] = o;
            }
        }
    } else {
        int base = (id - TT - 1024) * 256 + tid;
        int stride = 1024 * 256;
        int n = BB * NN * (NN / 16);
        for (int i = base; i < n; i += stride) {
            const float4v* mp = (const float4v*)(a.mask + (size_t)i * 16);
            unsigned int bits = 0;
#pragma unroll
            for (int q = 0; q < 4; ++q) {
                float4v v = mp[q];
#pragma unroll
                for (int j = 0; j < 4; ++j) bits |= (v[j] > 0.5f) ? (1u << (q * 4 + j)) : 0u;
            }
            a.mb[i] = (unsigned short)bits;
        }
    }
}

// ---------------- LayerNorm (standalone, for LN2) ----------------
__global__ __launch_bounds__(256) void ln_kernel(const float* __restrict__ x,
                                                 const float* __restrict__ g,
                                                 const float* __restrict__ b,
                                                 unsigned short* __restrict__ out) {
    int t = blockIdx.x;
    int tid = threadIdx.x;
    const float* xr = x + (size_t)t * CC;
    float v0 = xr[tid], v1 = xr[tid + 256], v2 = xr[tid + 512];
    float s = v0 + v1 + v2;
    float s2 = v0 * v0 + v1 * v1 + v2 * v2;
#pragma unroll
    for (int off = 1; off < 64; off <<= 1) {
        s  += __shfl_xor(s, off);
        s2 += __shfl_xor(s2, off);
    }
    __shared__ float red[8];
    int wv = tid >> 6, lane = tid & 63;
    if (lane == 0) { red[wv] = s; red[wv + 4] = s2; }
    __syncthreads();
    s  = red[0] + red[1] + red[2] + red[3];
    s2 = red[4] + red[5] + red[6] + red[7];
    float mu   = s * (1.0f / CC);
    float var  = s2 * (1.0f / CC) - mu * mu;
    float rstd = rsqrtf(var + 1e-5f);
    unsigned short* orow = out + (size_t)t * CC;
    orow[tid]       = f2bf((v0 - mu) * rstd * g[tid]       + b[tid]);
    orow[tid + 256] = f2bf((v1 - mu) * rstd * g[tid + 256] + b[tid + 256]);
    orow[tid + 512] = f2bf((v2 - mu) * rstd * g[tid + 512] + b[tid + 512]);
}

// ---------------- GEMM (R9 config, best measured): dbuf + counted vmcnt ----
// C[M,N] = A[M,K] @ Bw[N,K]^T (+epilogue). BK=32, BN=128.
// EPI 0: bf16; 1: +bias+res->f32; 2: +bias+GELU->bf16; 3: +bias+res->f32
template <int EPI, int BM>
__global__ __launch_bounds__(256) void gemm_bt(const unsigned short* __restrict__ A,
                                               const unsigned short* __restrict__ Bw,
                                               const float* __restrict__ bias,
                                               const float* __restrict__ res,
                                               void* __restrict__ out,
                                               int M, int N, int K) {
    constexpr int MI = BM / 32;           // 4 (BM=128) or 2 (BM=64)
    constexpr int NCA = (BM * 4) / 256;   // A chunks per thread: 2 or 1
    __shared__ alignas(16) unsigned short As[2][BM * 32];
    __shared__ alignas(16) unsigned short Bs[2][128 * 32];
    int tid = threadIdx.x;
    int lane = tid & 63, wv = tid >> 6;
    int l16 = lane & 15, lg = lane >> 4;
    int bm = blockIdx.x, bn = blockIdx.y;
    int wm = (wv & 1) * (BM / 2), wn = (wv >> 1) * 64;

    const unsigned short* Ab = A + (size_t)bm * BM * K;
    const unsigned short* Bb = Bw + (size_t)bn * 128 * K;

    const unsigned short* aSrc[NCA]; int aDst[NCA];
#pragma unroll
    for (int i = 0; i < NCA; ++i) {
        int c = tid + i * 256;
        int row = c >> 2, p = c & 3;
        int lc = p ^ ((row >> 1) & 3);
        aSrc[i] = Ab + (size_t)row * K + lc * 8;
        aDst[i] = c * 8;
    }
    const unsigned short* bSrc[2]; int bDst[2];
#pragma unroll
    for (int i = 0; i < 2; ++i) {
        int c = tid + i * 256;
        int row = c >> 2, p = c & 3;
        int lc = p ^ ((row >> 1) & 3);
        bSrc[i] = Bb + (size_t)row * K + lc * 8;
        bDst[i] = c * 8;
    }
    int aoff = (wm + l16) * 32 + ((lg ^ (((wm + l16) >> 1) & 3)) * 8);
    int boff = (wn + l16) * 32 + ((lg ^ (((wn + l16) >> 1) & 3)) * 8);

    f32x4 acc[MI][4];
#pragma unroll
    for (int i = 0; i < MI; ++i)
#pragma unroll
        for (int j = 0; j < 4; ++j) acc[i][j] = f32x4{0.f, 0.f, 0.f, 0.f};

    auto STAGE = [&](int s, int k0) {
#pragma unroll
        for (int i = 0; i < NCA; ++i) gload16(aSrc[i] + k0, &As[s][aDst[i]]);
#pragma unroll
        for (int i = 0; i < 2; ++i)   gload16(bSrc[i] + k0, &Bs[s][bDst[i]]);
    };

    STAGE(0, 0);
    int nt = K / 32;
    for (int t = 0; t < nt; ++t) {
        int cur = t & 1;
        if (t + 1 < nt) {
            STAGE(cur ^ 1, (t + 1) * 32);
            if constexpr (NCA + 2 == 4) { WAITV(4); } else { WAITV(3); }
        } else {
            WAITV(0);
        }
        __builtin_amdgcn_s_barrier();
        bf16x8 af[MI], bfr[4];
#pragma unroll
        for (int mi = 0; mi < MI; ++mi) af[mi]  = *(const bf16x8*)&As[cur][aoff + mi * 512];
#pragma unroll
        for (int ni = 0; ni < 4; ++ni)  bfr[ni] = *(const bf16x8*)&Bs[cur][boff + ni * 512];
#pragma unroll
        for (int mi = 0; mi < MI; ++mi)
#pragma unroll
            for (int ni = 0; ni < 4; ++ni)
                acc[mi][ni] = __builtin_amdgcn_mfma_f32_16x16x32_bf16(bfr[ni], af[mi], acc[mi][ni], 0, 0, 0);
        WAITLGKM;
        __builtin_amdgcn_s_barrier();
    }

    // vector epilogue: row = ...+l16, cols = base+lg*4+(0..3)
#pragma unroll
    for (int mi = 0; mi < MI; ++mi) {
        int row = bm * BM + wm + mi * 16 + l16;
#pragma unroll
        for (int ni = 0; ni < 4; ++ni) {
            int col = bn * 128 + wn + ni * 16 + lg * 4;
            size_t idx = (size_t)row * N + col;
            f32x4 v = acc[mi][ni];
            if (EPI == 0) {
                bf16x4 ov;
#pragma unroll
                for (int r2 = 0; r2 < 4; ++r2) ov[r2] = (short)f2bf(v[r2]);
                *(bf16x4*)((unsigned short*)out + idx) = ov;
            } else if (EPI == 1 || EPI == 3) {
                f32x4 bv = *(const f32x4*)&bias[col];
                f32x4 rv = *(const f32x4*)&res[idx];
                f32x4 ov;
#pragma unroll
                for (int r2 = 0; r2 < 4; ++r2) ov[r2] = v[r2] + bv[r2] + rv[r2];
                *(f32x4*)((float*)out + idx) = ov;
            } else {
                f32x4 bv = *(const f32x4*)&bias[col];
                bf16x4 ov;
#pragma unroll
                for (int r2 = 0; r2 < 4; ++r2) {
                    float t2 = v[r2] + bv[r2];
                    t2 = 0.5f * t2 * (1.0f + erff(t2 * 0.70710678118f));
                    ov[r2] = (short)f2bf(t2);
                }
                *(bf16x4*)((unsigned short*)out + idx) = ov;
            }
        }
    }
}

// ---------------- Flash attention v9: split-KV x2 (shift-free softmax => exact merge) ----
// 1536 blocks (6/CU, 24 waves/CU) vs 768: attacks the ~34% idle (R13: MfmaUtil 21
// + VALUBusy 45 = 66% busy at 3 blocks/CU). Each block does 16 of 32 KV tiles,
// writes UNNORMALIZED O (f32) and partial l; combine: O=(O0+O1)/(l0+l1) exact.
#define KVB 64
#define HNT 16         // tiles per half
#define VP 68          // Vt pitch (ushorts)
__global__ __launch_bounds__(256) void attn_kernel(const unsigned short* __restrict__ qkv,
                                                   const unsigned short* __restrict__ maskb,
                                                   float* __restrict__ Op,   // [2][TT*CC]
                                                   float* __restrict__ lp) { // [2][TT*HH]
    __shared__ alignas(16) unsigned short Ks[2][64 * 64];
    __shared__ alignas(16) unsigned short Vt[2][64 * VP];
    int tid = threadIdx.x;
    int lane = tid & 63, wv = tid >> 6;
    int l16 = lane & 15, lg = lane >> 4;
    int id = blockIdx.x;                 // 0..1535
    int half = id & 1;
    int rid = id >> 1;                   // 0..767
    int xcd = rid & 7, r = rid >> 3;     // r 0..95
    int bh = xcd * 3 + (r % 3);          // 0..23
    int qb = r / 3;                      // 0..31
    int b = bh / HH, h = bh % HH;
    int qrow = qb * 64 + wv * 16 + l16;
    int kt0 = half * HNT;

    const unsigned short* qp = qkv + ((size_t)(b * NN + qrow)) * 2304 + h * DD;
    bf16x8 q0r = *(const bf16x8*)(qp + 8 * lg);
    bf16x8 q1r = *(const bf16x8*)(qp + 32 + 8 * lg);
    const float QSC = 0.125f * 1.4426950408889634f;
    bf16x8 q0, q1;
#pragma unroll
    for (int j = 0; j < 8; ++j) {
        q0[j] = (short)f2bf(bf2f((unsigned short)q0r[j]) * QSC);
        q1[j] = (short)f2bf(bf2f((unsigned short)q1r[j]) * QSC);
    }

    const unsigned short* mrow  = maskb + ((size_t)(b * NN + qrow)) * 128;
    const unsigned short* kbase = qkv + (size_t)b * NN * 2304 + 768 + h * DD;
    const unsigned short* vbase = qkv + (size_t)b * NN * 2304 + 1536 + h * DD;

    const unsigned short* kSrc[2]; int kDst[2];
#pragma unroll
    for (int i = 0; i < 2; ++i) {
        int c = tid + i * 256;
        int row = c >> 3, p = c & 7;
        int lc = p ^ (row & 7);
        kSrc[i] = kbase + (size_t)row * 2304 + lc * 8;
        kDst[i] = c * 8;
    }
    int kp = tid & 31, dg = tid >> 5;
    const unsigned short* vSrc = vbase + (size_t)(2 * kp) * 2304 + dg * 8;

    int sw = l16 & 7;
    int kb0 = l16 * 64 + ((lg ^ sw) * 8);
    int kb1 = l16 * 64 + (((lg + 4) ^ sw) * 8);
    int vbo = l16 * VP + lg * 4;

    bf16x8 va, vb;
    unsigned long long mb_cur, mb_nxt;

    f32x4 oa[4];
#pragma unroll
    for (int i = 0; i < 4; ++i) oa[i] = f32x4{0.f, 0.f, 0.f, 0.f};
    float lrun = 0.f;

    // V + mask FIRST, then K-dma: counted WAITV(2) leaves only K-dma in flight.
    auto LOAD = [&](int t, int s) {
        const unsigned short* vp = vSrc + (size_t)t * KVB * 2304;
        va = *(const bf16x8*)(vp);
        vb = *(const bf16x8*)(vp + 2304);
        mb_nxt = *(const unsigned long long*)(mrow + t * 4);
        __builtin_amdgcn_sched_barrier(0);
#pragma unroll
        for (int i = 0; i < 2; ++i) gload16(kSrc[i] + (size_t)t * KVB * 2304, &Ks[s][kDst[i]]);
    };
    auto WRITEV = [&](int s) {
        unsigned int* VtU = (unsigned int*)Vt[s];
#pragma unroll
        for (int j = 0; j < 8; ++j)
            VtU[(dg * 8 + j) * (VP / 2) + kp] =
                (unsigned int)(unsigned short)va[j] | ((unsigned int)(unsigned short)vb[j] << 16);
    };

    LOAD(kt0, 0);
    WAITV(2);
    WRITEV(0);
    mb_cur = mb_nxt;
    int cur = 0;

    for (int t = 0; t < HNT; ++t) {
        bool pre = (t + 1 < HNT);
        WAITV(0);
        WAITLGKM;
        __builtin_amdgcn_s_barrier();
        if (pre) LOAD(kt0 + t + 1, cur ^ 1);

        const unsigned short* Ksc = Ks[cur];
        const unsigned short* Vtc = Vt[cur];

        float ps = 0.f;
        bf16x4 pf[4];
#pragma unroll
        for (int ks = 0; ks < 4; ++ks) {
            bf16x8 k0 = *(const bf16x8*)&Ksc[kb0 + ks * 1024];
            bf16x8 k1 = *(const bf16x8*)&Ksc[kb1 + ks * 1024];
            f32x4 sa = f32x4{0.f, 0.f, 0.f, 0.f};
            sa = __builtin_amdgcn_mfma_f32_16x16x32_bf16(k0, q0, sa, 0, 0, 0);
            sa = __builtin_amdgcn_mfma_f32_16x16x32_bf16(k1, q1, sa, 0, 0, 0);
            unsigned int m16 = (unsigned int)(mb_cur >> (ks * 16 + lg * 4));
#pragma unroll
            for (int r2 = 0; r2 < 4; ++r2) {
                float mbit = (float)((m16 >> r2) & 1u);
                float p = EXP2F(fmaf(mbit, -144269.5f, sa[r2]));
                ps += p;
                pf[ks][r2] = (short)(__float_as_uint(p) >> 16);   // truncating bf16 (p>=0)
            }
        }
        lrun += ps;

#pragma unroll
        for (int ks = 0; ks < 4; ++ks)
#pragma unroll
            for (int db = 0; db < 4; ++db) {
                bf16x4 vf = *(const bf16x4*)&Vtc[vbo + db * 16 * VP + ks * 16];
                oa[db] = __builtin_amdgcn_mfma_f32_16x16x16bf16_1k(vf, pf[ks], oa[db], 0, 0, 0);
            }

        if (pre) {
            WAITV(2);
            WRITEV(cur ^ 1);
            cur ^= 1;
            mb_cur = mb_nxt;
        }
    }

    // l partial: sum across lg groups (lanes l16,l16+16,+32,+48 end identical)
    float lt = lrun;
    lt += __shfl_xor(lt, 16);
    lt += __shfl_xor(lt, 32);
    lp[(size_t)half * TT * HH + (size_t)(b * NN + qrow) * HH + h] = lt;

    // unnormalized O partial (f32)
    float* opf = Op + (size_t)half * TT * CC + (size_t)(b * NN + qrow) * CC + h * DD;
#pragma unroll
    for (int db = 0; db < 4; ++db)
        *(f32x4*)&opf[db * 16 + lg * 4] = oa[db];
}

// ---------------- split-KV combine: obuf = (O0+O1)/(l0+l1), bf16 ----------------
__global__ __launch_bounds__(256) void combine_kernel(const float* __restrict__ Op,
                                                      const float* __restrict__ lp,
                                                      unsigned short* __restrict__ obuf) {
    int i8 = blockIdx.x * 256 + threadIdx.x;     // chunk of 8 floats; 96 chunks/row
    size_t i = (size_t)i8 * 8;
    int token = i8 / 96;
    int c8 = i8 % 96;
    int h = c8 >> 3;                              // 8 chunks per head
    size_t lidx = (size_t)token * HH + h;
    float ls = lp[lidx] + lp[(size_t)TT * HH + lidx];
    float inv = 1.0f / ls;
    const float* O0 = Op;
    const float* O1 = Op + (size_t)TT * CC;
    f32x4 a0 = *(const f32x4*)&O0[i];
    f32x4 a1 = *(const f32x4*)&O0[i + 4];
    f32x4 b0 = *(const f32x4*)&O1[i];
    f32x4 b1 = *(const f32x4*)&O1[i + 4];
    ushort8v o;
#pragma unroll
    for (int j = 0; j < 4; ++j) o[j]     = f2bf((a0[j] + b0[j]) * inv);
#pragma unroll
    for (int j = 0; j < 4; ++j) o[4 + j] = f2bf((a1[j] + b1[j]) * inv);
    *(ushort8v*)&obuf[i] = o;
}

// ---------------- host launch ----------------
extern "C" void kernel_launch(void* const* d_in, const int* in_sizes, int n_in,
                              void* d_out, int out_size, void* d_ws, size_t ws_size,
                              hipStream_t stream) {
    const float* x    = (const float*)d_in[0];
    const float* mask = (const float*)d_in[1];
    const float* g1   = (const float*)d_in[2];
    const float* b1   = (const float*)d_in[3];
    const float* Wq   = (const float*)d_in[4];
    const float* Wkv  = (const float*)d_in[5];
    const float* Wp   = (const float*)d_in[6];
    const float* bp   = (const float*)d_in[7];
    const float* g2   = (const float*)d_in[8];
    const float* b2   = (const float*)d_in[9];
    const float* W1   = (const float*)d_in[10];
    const float* bf1  = (const float*)d_in[11];
    const float* W2   = (const float*)d_in[12];
    const float* bf2  = (const float*)d_in[13];
    float* out = (float*)d_out;

    char* w = (char*)d_ws;
    unsigned short* wqkv = (unsigned short*)w;      w += (size_t)2304 * 768 * 2;
    unsigned short* wp   = (unsigned short*)w;      w += (size_t)768 * 768 * 2;
    unsigned short* w1   = (unsigned short*)w;      w += (size_t)3072 * 768 * 2;
    unsigned short* w2   = (unsigned short*)w;      w += (size_t)768 * 3072 * 2;
    unsigned short* xn   = (unsigned short*)w;      w += (size_t)TT * CC * 2;
    unsigned short* qkv  = (unsigned short*)w;      w += (size_t)TT * 2304 * 2;
    unsigned short* mb   = (unsigned short*)w;      w += (size_t)BB * NN * 128 * 2;
    unsigned short* obuf = (unsigned short*)w;      w += (size_t)TT * CC * 2;
    float*          x1   = (float*)w;               w += (size_t)TT * CC * 4;
    unsigned short* xn2  = (unsigned short*)w;      w += (size_t)TT * CC * 2;
    unsigned short* hbuf = (unsigned short*)w;      w += (size_t)TT * HID * 2;

    // region reuse (stream-ordered, no overlap in lifetime):
    //   Op (2 x TT*CC f32 = 25.2 MB) lives in hbuf region (fc1 writes hbuf later)
    //   lp (2 x TT*HH f32 = 0.4 MB)  lives in x1 region   (proj writes x1 later)
    float* Op = (float*)hbuf;
    float* lp = (float*)x1;

    PrepArgs pa;
    pa.x = x; pa.g1 = g1; pa.b1 = b1; pa.xn = xn;
    pa.cin[0] = Wq;  pa.cout[0] = wqkv;             pa.n4[0] = 768 * 768 / 4;
    pa.cin[1] = Wkv; pa.cout[1] = wqkv + 768 * 768; pa.n4[1] = 1536 * 768 / 4;
    pa.cin[2] = Wp;  pa.cout[2] = wp;               pa.n4[2] = 768 * 768 / 4;
    pa.cin[3] = W1;  pa.cout[3] = w1;               pa.n4[3] = 3072 * 768 / 4;
    pa.cin[4] = W2;  pa.cout[4] = w2;               pa.n4[4] = 768 * 3072 / 4;
    pa.mask = mask; pa.mb = mb;
    prep_kernel<<<TT + 2048, 256, 0, stream>>>(pa);

    // qkv: M=4096 N=2304 K=768 (R9 config)
    gemm_bt<0, 128><<<dim3(TT / 128, 2304 / 128), 256, 0, stream>>>(xn, wqkv, nullptr, nullptr, qkv, TT, 2304, 768);

    // attention: split-KV x2 -> 1536 blocks
    attn_kernel<<<1536, 256, 0, stream>>>(qkv, mb, Op, lp);
    combine_kernel<<<TT * CC / 8 / 256, 256, 0, stream>>>(Op, lp, obuf);

    // proj: M=4096 N=768 K=768 (R9 config)
    gemm_bt<1, 64><<<dim3(TT / 64, 768 / 128), 256, 0, stream>>>(obuf, wp, bp, x, x1, TT, 768, 768);

    ln_kernel<<<TT, 256, 0, stream>>>(x1, g2, b2, xn2);

    // fc1: M=4096 N=3072 K=768 (R9 config)
    gemm_bt<2, 128><<<dim3(TT / 128, HID / 128), 256, 0, stream>>>(xn2, w1, bf1, nullptr, hbuf, TT, HID, 768);

    // fc2: M=4096 N=768 K=3072 (R9 config)
    gemm_bt<3, 64><<<dim3(TT / 64, 768 / 128), 256, 0, stream>>>(hbuf, w2, bf2, x1, out, TT, 768, HID);
}